// Round 1
// baseline (5453.068 us; speedup 1.0000x reference)
//
#include <hip/hip_runtime.h>

// Node model GNN:
//   edge: h = relu(relu([x[src],ea] @ W1 + b1) @ W2 + b2)   (W3 commuted past scatter-mean)
//   node: agg = mean_scatter(h); a3 = agg@W3+b3; z = relu([x,a3,u[batch]]@W4+b4) @ W5 + b5
constexpr int HID = 64;

__device__ __forceinline__ void atomF(float* p, float v) {
    __hip_atomic_fetch_add(p, v, __ATOMIC_RELAXED, __HIP_MEMORY_SCOPE_AGENT);
}

__global__ __launch_bounds__(128) void edge_kernel(
    const float* __restrict__ x,    // [N,2]
    const int*   __restrict__ ei,   // [2,E]
    const float* __restrict__ ea,   // [E,1]
    const float* __restrict__ W1, const float* __restrict__ b1,  // (3,64),(64)
    const float* __restrict__ W2, const float* __restrict__ b2,  // (64,64),(64)
    float* __restrict__ agg,        // [N,64] running sums
    float* __restrict__ cnt,        // [N]
    int E)
{
    // h1 staged transposed: h1s[k*128 + tid] -> stride-128-word columns, 2 lanes/bank (free)
    __shared__ float h1s[HID * 128];
    const int tid = threadIdx.x;
    const int e = blockIdx.x * 128 + tid;
    const bool valid = (e < E);
    int src = 0, dst = 0;
    float x0 = 0.f, x1 = 0.f, w = 0.f;
    if (valid) {
        src = ei[e];
        dst = ei[E + e];
        x0 = x[2 * src];
        x1 = x[2 * src + 1];
        w  = ea[e];
    }

    // layer 1: [3] -> [64], weights wave-uniform (s_load)
    #pragma unroll
    for (int j = 0; j < HID; ++j) {
        float v = b1[j];
        v = fmaf(x0, W1[j],        v);
        v = fmaf(x1, W1[HID + j],  v);
        v = fmaf(w,  W1[2*HID + j], v);
        h1s[j * 128 + tid] = fmaxf(v, 0.f);
    }

    // layer 2: [64] -> [64], h2 in registers (static indexing only)
    float h2[HID];
    #pragma unroll
    for (int j = 0; j < HID; ++j) h2[j] = b2[j];
    #pragma unroll 4
    for (int k = 0; k < HID; ++k) {
        const float hk = h1s[k * 128 + tid];
        const float* wr = W2 + k * HID;
        #pragma unroll
        for (int j = 0; j < HID; ++j) h2[j] = fmaf(hk, wr[j], h2[j]);
    }

    // scatter relu(h2) into agg[dst], count edges per dst
    if (valid) {
        float* dp = agg + (size_t)dst * HID;
        #pragma unroll
        for (int j = 0; j < HID; ++j) atomF(dp + j, fmaxf(h2[j], 0.f));
        atomF(cnt + dst, 1.0f);
    }
}

__global__ __launch_bounds__(128) void node_kernel(
    const float* __restrict__ x,     // [N,2]
    const float* __restrict__ u,     // [64]
    const int*   __restrict__ batch, // [N]
    const float* __restrict__ W3, const float* __restrict__ b3,  // (64,64),(64)
    const float* __restrict__ W4, const float* __restrict__ b4,  // (67,67),(67)
    const float* __restrict__ W5, const float* __restrict__ b5,  // (67,2),(2)
    const float* __restrict__ agg, const float* __restrict__ cnt,
    float* __restrict__ out,         // [N,2]
    int N)
{
    __shared__ float zs[67 * 128];   // transposed per-thread columns
    const int tid = threadIdx.x;
    const int n = blockIdx.x * 128 + tid;
    const bool valid = (n < N);
    const int nn = valid ? n : 0;

    const float c = cnt[nn];
    const float inv = 1.f / fmaxf(c, 1.f);
    const float* ar = agg + (size_t)nn * HID;

    // stage mean(h) into zs rows [2..65]
    #pragma unroll
    for (int k = 0; k < HID; ++k) zs[(2 + k) * 128 + tid] = ar[k] * inv;

    // a3 = mean @ W3 + b3
    float a3[HID];
    #pragma unroll
    for (int j = 0; j < HID; ++j) a3[j] = b3[j];
    #pragma unroll 4
    for (int k = 0; k < HID; ++k) {
        const float mk = zs[(2 + k) * 128 + tid];
        const float* wr = W3 + k * HID;
        #pragma unroll
        for (int j = 0; j < HID; ++j) a3[j] = fmaf(mk, wr[j], a3[j]);
    }

    // build zin = [x0, x1, a3[0..63], u[batch]] in zs (overwrite rows 2..65 after reads done)
    const float x0 = x[2 * nn];
    const float x1 = x[2 * nn + 1];
    const float ub = u[batch[nn]];
    zs[0 * 128 + tid] = x0;
    zs[1 * 128 + tid] = x1;
    #pragma unroll
    for (int j = 0; j < HID; ++j) zs[(2 + j) * 128 + tid] = a3[j];
    zs[66 * 128 + tid] = ub;

    // z4 = relu(zin @ W4 + b4)  [67], fused with out = z4 @ W5 + b5
    float acc[67];
    #pragma unroll
    for (int j = 0; j < 67; ++j) acc[j] = b4[j];
    #pragma unroll 4
    for (int k = 0; k < 67; ++k) {
        const float zk = zs[k * 128 + tid];
        const float* wr = W4 + k * 67;
        #pragma unroll
        for (int j = 0; j < 67; ++j) acc[j] = fmaf(zk, wr[j], acc[j]);
    }

    float o0 = b5[0], o1 = b5[1];
    #pragma unroll
    for (int j = 0; j < 67; ++j) {
        const float z4 = fmaxf(acc[j], 0.f);
        o0 = fmaf(z4, W5[2 * j],     o0);
        o1 = fmaf(z4, W5[2 * j + 1], o1);
    }
    if (valid) {
        out[2 * n]     = o0;
        out[2 * n + 1] = o1;
    }
}

extern "C" void kernel_launch(void* const* d_in, const int* in_sizes, int n_in,
                              void* d_out, int out_size, void* d_ws, size_t ws_size,
                              hipStream_t stream) {
    const float* x     = (const float*)d_in[0];
    const int*   ei    = (const int*)  d_in[1];
    const float* ea    = (const float*)d_in[2];
    const float* u     = (const float*)d_in[3];
    const int*   batch = (const int*)  d_in[4];
    const float* W1 = (const float*)d_in[5];  const float* b1 = (const float*)d_in[6];
    const float* W2 = (const float*)d_in[7];  const float* b2 = (const float*)d_in[8];
    const float* W3 = (const float*)d_in[9];  const float* b3 = (const float*)d_in[10];
    const float* W4 = (const float*)d_in[11]; const float* b4 = (const float*)d_in[12];
    const float* W5 = (const float*)d_in[13]; const float* b5 = (const float*)d_in[14];

    const int N = in_sizes[0] / 2;   // 100000
    const int E = in_sizes[2];       // 1600000 (edge_attr count)

    float* agg = (float*)d_ws;               // [N,64]
    float* cnt = agg + (size_t)N * HID;      // [N]

    hipMemsetAsync(d_ws, 0, ((size_t)N * HID + N) * sizeof(float), stream);

    edge_kernel<<<(E + 127) / 128, 128, 0, stream>>>(x, ei, ea, W1, b1, W2, b2, agg, cnt, E);
    node_kernel<<<(N + 127) / 128, 128, 0, stream>>>(x, u, batch, W3, b3, W4, b4, W5, b5,
                                                     agg, cnt, (float*)d_out, N);
}

// Round 2
// 493.414 us; speedup vs baseline: 11.0517x; 11.0517x over previous
//
#include <hip/hip_runtime.h>

// Node model GNN, CSR-pull formulation:
//   edge MLP: h = relu(relu([x[src],ea]@W1+b1)@W2+b2)     (W3 commuted past the mean)
//   aggT[j][n] = mean_{e: dst(e)=n} h[e][j]
//   node: a3 = mean@W3+b3; out = relu([x,a3,u[batch]]@W4+b4)@W5+b5
constexpr int HID = 64;

// ---------- pass 1: in-degree histogram (400KB counter array, L2-resident) ----------
__global__ __launch_bounds__(256) void count_kernel(
    const int* __restrict__ ei, int* __restrict__ counts, int E)
{
    int e = blockIdx.x * 256 + threadIdx.x;
    if (e < E) atomicAdd(&counts[ei[E + e]], 1);
}

// ---------- pass 2a: per-1024-element block sums ----------
__global__ __launch_bounds__(256) void scan1_kernel(
    const int* __restrict__ counts, int* __restrict__ partials, int N)
{
    __shared__ int red[256];
    const int base = blockIdx.x * 1024;
    int s = 0;
    #pragma unroll
    for (int r = 0; r < 4; ++r) {
        int i = base + r * 256 + threadIdx.x;
        s += (i < N) ? counts[i] : 0;
    }
    red[threadIdx.x] = s;
    __syncthreads();
    for (int off = 128; off > 0; off >>= 1) {
        if (threadIdx.x < off) red[threadIdx.x] += red[threadIdx.x + off];
        __syncthreads();
    }
    if (threadIdx.x == 0) partials[blockIdx.x] = red[0];
}

// ---------- pass 2b: exclusive scan of block sums (single block), writes offsets[N]=E ----------
__global__ __launch_bounds__(256) void scan2_kernel(
    int* __restrict__ partials, int nb, int* __restrict__ offsets, int N)
{
    __shared__ int sm[256];
    __shared__ int carry_s;
    if (threadIdx.x == 0) carry_s = 0;
    __syncthreads();
    for (int base = 0; base < nb; base += 256) {
        int i = base + threadIdx.x;
        int v = (i < nb) ? partials[i] : 0;
        sm[threadIdx.x] = v;
        __syncthreads();
        for (int off = 1; off < 256; off <<= 1) {
            int t = (threadIdx.x >= off) ? sm[threadIdx.x - off] : 0;
            __syncthreads();
            sm[threadIdx.x] += t;
            __syncthreads();
        }
        int incl = sm[threadIdx.x];
        int carry = carry_s;
        __syncthreads();
        if (i < nb) partials[i] = incl - v + carry;
        if (threadIdx.x == 255) carry_s = carry + incl;
        __syncthreads();
    }
    if (threadIdx.x == 0) offsets[N] = carry_s;   // grand total == E
}

// ---------- pass 2c: per-element exclusive scan -> offsets & cursor ----------
__global__ __launch_bounds__(256) void scan3_kernel(
    const int* __restrict__ counts, const int* __restrict__ partials,
    int* __restrict__ offsets, int* __restrict__ cursor, int N)
{
    __shared__ int sm[256];
    const int tid = threadIdx.x;
    const int i0 = blockIdx.x * 1024 + tid * 4;
    int v[4];
    #pragma unroll
    for (int r = 0; r < 4; ++r) v[r] = (i0 + r < N) ? counts[i0 + r] : 0;
    const int tsum = v[0] + v[1] + v[2] + v[3];
    sm[tid] = tsum;
    __syncthreads();
    for (int off = 1; off < 256; off <<= 1) {
        int t = (tid >= off) ? sm[tid - off] : 0;
        __syncthreads();
        sm[tid] += t;
        __syncthreads();
    }
    int excl = sm[tid] - tsum + partials[blockIdx.x];
    #pragma unroll
    for (int r = 0; r < 4; ++r) {
        if (i0 + r < N) { offsets[i0 + r] = excl; cursor[i0 + r] = excl; }
        excl += v[r];
    }
}

// ---------- pass 3: gather edge inputs into dest-sorted float4 array ----------
__global__ __launch_bounds__(256) void fill_kernel(
    const float* __restrict__ x, const int* __restrict__ ei,
    const float* __restrict__ ea, int* __restrict__ cursor,
    float4* __restrict__ ginp, int E)
{
    int e = blockIdx.x * 256 + threadIdx.x;
    if (e >= E) return;
    const int src = ei[e];
    const int dst = ei[E + e];
    const float w = ea[e];
    const float2 xv = ((const float2*)x)[src];
    const int pos = atomicAdd(&cursor[dst], 1);
    ginp[pos] = make_float4(xv.x, xv.y, w, 0.f);
}

// ---------- pass 4: per-dest edge MLP + mean, 16 lanes per node ----------
__global__ __launch_bounds__(256) void gather_kernel(
    const float4* __restrict__ ginp, const int* __restrict__ offsets,
    const float* __restrict__ W1, const float* __restrict__ b1,
    const float* __restrict__ W2, const float* __restrict__ b2,
    float* __restrict__ aggT,   // [HID][N] feature-major means
    int N)
{
    const int tid  = threadIdx.x;
    const int lane = tid & 15;
    const int node = blockIdx.x * 16 + (tid >> 4);
    if (node >= N) return;
    const int start = offsets[node];
    const int end   = offsets[node + 1];

    float acc[HID];
    #pragma unroll
    for (int j = 0; j < HID; ++j) acc[j] = 0.f;

    for (int i = start + lane; i < end; i += 16) {
        const float4 g = ginp[i];
        float h2[HID];
        #pragma unroll
        for (int j = 0; j < HID; ++j) h2[j] = b2[j];
        #pragma unroll 4
        for (int k = 0; k < HID; ++k) {
            float h1k = fmaf(g.x, W1[k], fmaf(g.y, W1[HID + k],
                        fmaf(g.z, W1[2 * HID + k], b1[k])));
            h1k = fmaxf(h1k, 0.f);
            const float* wr = W2 + k * HID;
            #pragma unroll
            for (int j = 0; j < HID; ++j) h2[j] = fmaf(h1k, wr[j], h2[j]);
        }
        #pragma unroll
        for (int j = 0; j < HID; ++j) acc[j] += fmaxf(h2[j], 0.f);
    }

    // 16-lane butterfly all-reduce (masks <16 stay within the group)
    #pragma unroll
    for (int j = 0; j < HID; ++j) {
        float v = acc[j];
        v += __shfl_xor(v, 1);
        v += __shfl_xor(v, 2);
        v += __shfl_xor(v, 4);
        v += __shfl_xor(v, 8);
        acc[j] = v;
    }

    const float inv = 1.f / fmaxf((float)(end - start), 1.f);
    #pragma unroll
    for (int j = 0; j < HID; ++j) {   // static j, predicated lane -> no runtime reg indexing
        if (lane == (j & 15)) aggT[(size_t)j * N + node] = acc[j] * inv;
    }
}

// ---------- pass 5: node MLP ----------
__global__ __launch_bounds__(256) void node_kernel(
    const float* __restrict__ x, const float* __restrict__ u,
    const int* __restrict__ batch,
    const float* __restrict__ W3, const float* __restrict__ b3,
    const float* __restrict__ W4, const float* __restrict__ b4,
    const float* __restrict__ W5, const float* __restrict__ b5,
    const float* __restrict__ aggT, float* __restrict__ out, int N)
{
    const int n = blockIdx.x * 256 + threadIdx.x;
    if (n >= N) return;

    float a3[HID];
    #pragma unroll
    for (int j = 0; j < HID; ++j) a3[j] = b3[j];
    #pragma unroll 4
    for (int k = 0; k < HID; ++k) {
        const float mk = aggT[(size_t)k * N + n];   // coalesced
        const float* wr = W3 + k * HID;
        #pragma unroll
        for (int j = 0; j < HID; ++j) a3[j] = fmaf(mk, wr[j], a3[j]);
    }

    const float2 xv = ((const float2*)x)[n];
    const float ub = u[batch[n]];
    float acc[67];
    #pragma unroll
    for (int j = 0; j < 67; ++j) acc[j] = b4[j];
    #pragma unroll
    for (int j = 0; j < 67; ++j) acc[j] = fmaf(xv.x, W4[j], acc[j]);
    #pragma unroll
    for (int j = 0; j < 67; ++j) acc[j] = fmaf(xv.y, W4[67 + j], acc[j]);
    #pragma unroll 4
    for (int k = 0; k < HID; ++k) {
        const float* wr = W4 + (2 + k) * 67;
        #pragma unroll
        for (int j = 0; j < 67; ++j) acc[j] = fmaf(a3[k], wr[j], acc[j]);
    }
    #pragma unroll
    for (int j = 0; j < 67; ++j) acc[j] = fmaf(ub, W4[66 * 67 + j], acc[j]);

    float o0 = b5[0], o1 = b5[1];
    #pragma unroll
    for (int j = 0; j < 67; ++j) {
        const float z = fmaxf(acc[j], 0.f);
        o0 = fmaf(z, W5[2 * j], o0);
        o1 = fmaf(z, W5[2 * j + 1], o1);
    }
    out[2 * n] = o0;
    out[2 * n + 1] = o1;
}

extern "C" void kernel_launch(void* const* d_in, const int* in_sizes, int n_in,
                              void* d_out, int out_size, void* d_ws, size_t ws_size,
                              hipStream_t stream) {
    const float* x     = (const float*)d_in[0];
    const int*   ei    = (const int*)  d_in[1];
    const float* ea    = (const float*)d_in[2];
    const float* u     = (const float*)d_in[3];
    const int*   batch = (const int*)  d_in[4];
    const float* W1 = (const float*)d_in[5];  const float* b1 = (const float*)d_in[6];
    const float* W2 = (const float*)d_in[7];  const float* b2 = (const float*)d_in[8];
    const float* W3 = (const float*)d_in[9];  const float* b3 = (const float*)d_in[10];
    const float* W4 = (const float*)d_in[11]; const float* b4 = (const float*)d_in[12];
    const float* W5 = (const float*)d_in[13]; const float* b5 = (const float*)d_in[14];

    const int N = in_sizes[0] / 2;   // 100000
    const int E = in_sizes[2];       // 1600000

    // workspace layout
    char* w = (char*)d_ws;
    size_t o = 0;
    int* counts   = (int*)(w + o); o += (size_t)N * 4;
    int* offsets  = (int*)(w + o); o += (size_t)(N + 1) * 4;
    int* cursor   = (int*)(w + o); o += (size_t)N * 4;
    int* partials = (int*)(w + o); o += 4096 * 4;
    o = (o + 15) & ~(size_t)15;
    float4* ginp  = (float4*)(w + o); o += (size_t)E * 16;
    float* aggT   = (float*)(w + o);  o += (size_t)HID * N * 4;

    const int nb1 = (N + 1023) / 1024;

    hipMemsetAsync(counts, 0, (size_t)N * 4, stream);
    count_kernel<<<(E + 255) / 256, 256, 0, stream>>>(ei, counts, E);
    scan1_kernel<<<nb1, 256, 0, stream>>>(counts, partials, N);
    scan2_kernel<<<1, 256, 0, stream>>>(partials, nb1, offsets, N);
    scan3_kernel<<<nb1, 256, 0, stream>>>(counts, partials, offsets, cursor, N);
    fill_kernel<<<(E + 255) / 256, 256, 0, stream>>>(x, ei, ea, cursor, ginp, E);
    gather_kernel<<<(N + 15) / 16, 256, 0, stream>>>(ginp, offsets, W1, b1, W2, b2, aggT, N);
    node_kernel<<<(N + 255) / 256, 256, 0, stream>>>(x, u, batch, W3, b3, W4, b4, W5, b5,
                                                     aggT, (float*)d_out, N);
}

// Round 3
// 442.551 us; speedup vs baseline: 12.3219x; 1.1149x over previous
//
#include <hip/hip_runtime.h>

// Node model GNN, CSR-pull + flat segmented-reduce formulation:
//   edge MLP: h = relu(relu([x[src],ea]@W1+b1)@W2+b2)   (W3 commuted past the mean)
//   agg[n][j] = sum_{e: dst(e)=n} h[e][j]   (mean division done in node kernel)
//   node: a3 = (agg/cnt)@W3+b3; out = relu([x,a3,u[batch]]@W4+b4)@W5+b5
constexpr int HID = 64;

__device__ __forceinline__ void atomF(float* p, float v) {
    __hip_atomic_fetch_add(p, v, __ATOMIC_RELAXED, __HIP_MEMORY_SCOPE_AGENT);
}

// ---------- pass 1: in-degree histogram (400KB counter array, L2-resident) ----------
__global__ __launch_bounds__(256) void count_kernel(
    const int* __restrict__ ei, int* __restrict__ counts, int E)
{
    int e = blockIdx.x * 256 + threadIdx.x;
    if (e < E) atomicAdd(&counts[ei[E + e]], 1);
}

// ---------- pass 2a: per-1024-element block sums ----------
__global__ __launch_bounds__(256) void scan1_kernel(
    const int* __restrict__ counts, int* __restrict__ partials, int N)
{
    __shared__ int red[256];
    const int base = blockIdx.x * 1024;
    int s = 0;
    #pragma unroll
    for (int r = 0; r < 4; ++r) {
        int i = base + r * 256 + threadIdx.x;
        s += (i < N) ? counts[i] : 0;
    }
    red[threadIdx.x] = s;
    __syncthreads();
    for (int off = 128; off > 0; off >>= 1) {
        if (threadIdx.x < off) red[threadIdx.x] += red[threadIdx.x + off];
        __syncthreads();
    }
    if (threadIdx.x == 0) partials[blockIdx.x] = red[0];
}

// ---------- pass 2b: exclusive scan of block sums (single block) ----------
__global__ __launch_bounds__(256) void scan2_kernel(
    int* __restrict__ partials, int nb, int* __restrict__ offsets, int N)
{
    __shared__ int sm[256];
    __shared__ int carry_s;
    if (threadIdx.x == 0) carry_s = 0;
    __syncthreads();
    for (int base = 0; base < nb; base += 256) {
        int i = base + threadIdx.x;
        int v = (i < nb) ? partials[i] : 0;
        sm[threadIdx.x] = v;
        __syncthreads();
        for (int off = 1; off < 256; off <<= 1) {
            int t = (threadIdx.x >= off) ? sm[threadIdx.x - off] : 0;
            __syncthreads();
            sm[threadIdx.x] += t;
            __syncthreads();
        }
        int incl = sm[threadIdx.x];
        int carry = carry_s;
        __syncthreads();
        if (i < nb) partials[i] = incl - v + carry;
        if (threadIdx.x == 255) carry_s = carry + incl;
        __syncthreads();
    }
    if (threadIdx.x == 0) offsets[N] = carry_s;   // grand total == E
}

// ---------- pass 2c: per-element exclusive scan -> offsets & cursor ----------
__global__ __launch_bounds__(256) void scan3_kernel(
    const int* __restrict__ counts, const int* __restrict__ partials,
    int* __restrict__ offsets, int* __restrict__ cursor, int N)
{
    __shared__ int sm[256];
    const int tid = threadIdx.x;
    const int i0 = blockIdx.x * 1024 + tid * 4;
    int v[4];
    #pragma unroll
    for (int r = 0; r < 4; ++r) v[r] = (i0 + r < N) ? counts[i0 + r] : 0;
    const int tsum = v[0] + v[1] + v[2] + v[3];
    sm[tid] = tsum;
    __syncthreads();
    for (int off = 1; off < 256; off <<= 1) {
        int t = (tid >= off) ? sm[tid - off] : 0;
        __syncthreads();
        sm[tid] += t;
        __syncthreads();
    }
    int excl = sm[tid] - tsum + partials[blockIdx.x];
    #pragma unroll
    for (int r = 0; r < 4; ++r) {
        if (i0 + r < N) { offsets[i0 + r] = excl; cursor[i0 + r] = excl; }
        excl += v[r];
    }
}

// ---------- pass 3: gather edge inputs into dest-sorted float4 array (dest in .w) ----------
__global__ __launch_bounds__(256) void fill_kernel(
    const float* __restrict__ x, const int* __restrict__ ei,
    const float* __restrict__ ea, int* __restrict__ cursor,
    float4* __restrict__ ginp, int E)
{
    int e = blockIdx.x * 256 + threadIdx.x;
    if (e >= E) return;
    const int src = ei[e];
    const int dst = ei[E + e];
    const float w = ea[e];
    const float2 xv = ((const float2*)x)[src];
    const int pos = atomicAdd(&cursor[dst], 1);
    ginp[pos] = make_float4(xv.x, xv.y, w, __int_as_float(dst));
}

// ---------- pass 4: flat edge MLP + wave segmented reduce ----------
// one thread per sorted edge; LDS transpose (stride 65, conflict-free);
// run boundaries wave-uniform via ballot; flush = coalesced 256B atomic burst
__global__ __launch_bounds__(128) void edge_mlp_kernel(
    const float4* __restrict__ ginp,
    const float* __restrict__ W1, const float* __restrict__ b1,
    const float* __restrict__ W2, const float* __restrict__ b2,
    float* __restrict__ agg,    // [N][64], pre-zeroed
    int E)
{
    __shared__ float hT[2][HID * 65];
    __shared__ int   dlds[2][64];
    const int tid  = threadIdx.x;
    const int wv   = tid >> 6;
    const int lane = tid & 63;
    const int e    = blockIdx.x * 128 + tid;

    float4 g = make_float4(0.f, 0.f, 0.f, __int_as_float(-1));
    if (e < E) g = ginp[e];
    const int dst = __float_as_int(g.w);

    // run-boundary mask (wave-uniform)
    const int dprev = __shfl_up(dst, 1);
    const bool start = (lane == 0) || (dprev != dst);
    const unsigned long long bmask = __ballot(start);
    const unsigned long long fmask = (bmask >> 1) | (1ull << 63);  // flush after e2 if next is a start
    dlds[wv][lane] = dst;

    // edge MLP
    float h2[HID];
    #pragma unroll
    for (int j = 0; j < HID; ++j) h2[j] = b2[j];
    #pragma unroll 4
    for (int k = 0; k < HID; ++k) {
        float h1k = fmaf(g.x, W1[k], fmaf(g.y, W1[HID + k],
                    fmaf(g.z, W1[2 * HID + k], b1[k])));
        h1k = fmaxf(h1k, 0.f);
        const float* wr = W2 + k * HID;
        #pragma unroll
        for (int j = 0; j < HID; ++j) h2[j] = fmaf(h1k, wr[j], h2[j]);
    }

    // transpose into LDS: hT[feat][edge_lane], stride 65 -> banks (j+lane)%32, conflict-free
    #pragma unroll
    for (int j = 0; j < HID; ++j) hT[wv][j * 65 + lane] = fmaxf(h2[j], 0.f);
    __syncthreads();

    // lane == feature; serial walk over the wave's 64 edges, flush at run ends
    float acc = 0.f;
    #pragma unroll
    for (int e2 = 0; e2 < 64; ++e2) {
        acc += hT[wv][lane * 65 + e2];            // banks (lane+e2)%32, conflict-free
        if ((fmask >> e2) & 1ull) {               // wave-uniform branch
            const int d = dlds[wv][e2];           // broadcast read
            if (d >= 0) atomF(&agg[(size_t)d * HID + lane], acc);  // 64 lanes -> 256B contiguous
            acc = 0.f;
        }
    }
}

// ---------- pass 5: node MLP ----------
__global__ __launch_bounds__(256) void node_kernel(
    const float* __restrict__ x, const float* __restrict__ u,
    const int* __restrict__ batch,
    const float* __restrict__ W3, const float* __restrict__ b3,
    const float* __restrict__ W4, const float* __restrict__ b4,
    const float* __restrict__ W5, const float* __restrict__ b5,
    const float* __restrict__ agg, const int* __restrict__ counts,
    float* __restrict__ out, int N)
{
    const int n = blockIdx.x * 256 + threadIdx.x;
    if (n >= N) return;

    const float inv = 1.f / fmaxf((float)counts[n], 1.f);
    const float4* ar = (const float4*)(agg + (size_t)n * HID);

    float a3[HID];
    #pragma unroll
    for (int j = 0; j < HID; ++j) a3[j] = b3[j];
    #pragma unroll 4
    for (int q = 0; q < HID / 4; ++q) {
        const float4 m4 = ar[q];
        const float mk[4] = {m4.x * inv, m4.y * inv, m4.z * inv, m4.w * inv};
        #pragma unroll
        for (int r = 0; r < 4; ++r) {
            const float* wr = W3 + (q * 4 + r) * HID;
            #pragma unroll
            for (int j = 0; j < HID; ++j) a3[j] = fmaf(mk[r], wr[j], a3[j]);
        }
    }

    const float2 xv = ((const float2*)x)[n];
    const float ub = u[batch[n]];
    float acc[67];
    #pragma unroll
    for (int j = 0; j < 67; ++j) acc[j] = b4[j];
    #pragma unroll
    for (int j = 0; j < 67; ++j) acc[j] = fmaf(xv.x, W4[j], acc[j]);
    #pragma unroll
    for (int j = 0; j < 67; ++j) acc[j] = fmaf(xv.y, W4[67 + j], acc[j]);
    #pragma unroll 4
    for (int k = 0; k < HID; ++k) {
        const float* wr = W4 + (2 + k) * 67;
        #pragma unroll
        for (int j = 0; j < 67; ++j) acc[j] = fmaf(a3[k], wr[j], acc[j]);
    }
    #pragma unroll
    for (int j = 0; j < 67; ++j) acc[j] = fmaf(ub, W4[66 * 67 + j], acc[j]);

    float o0 = b5[0], o1 = b5[1];
    #pragma unroll
    for (int j = 0; j < 67; ++j) {
        const float z = fmaxf(acc[j], 0.f);
        o0 = fmaf(z, W5[2 * j], o0);
        o1 = fmaf(z, W5[2 * j + 1], o1);
    }
    out[2 * n] = o0;
    out[2 * n + 1] = o1;
}

extern "C" void kernel_launch(void* const* d_in, const int* in_sizes, int n_in,
                              void* d_out, int out_size, void* d_ws, size_t ws_size,
                              hipStream_t stream) {
    const float* x     = (const float*)d_in[0];
    const int*   ei    = (const int*)  d_in[1];
    const float* ea    = (const float*)d_in[2];
    const float* u     = (const float*)d_in[3];
    const int*   batch = (const int*)  d_in[4];
    const float* W1 = (const float*)d_in[5];  const float* b1 = (const float*)d_in[6];
    const float* W2 = (const float*)d_in[7];  const float* b2 = (const float*)d_in[8];
    const float* W3 = (const float*)d_in[9];  const float* b3 = (const float*)d_in[10];
    const float* W4 = (const float*)d_in[11]; const float* b4 = (const float*)d_in[12];
    const float* W5 = (const float*)d_in[13]; const float* b5 = (const float*)d_in[14];

    const int N = in_sizes[0] / 2;   // 100000
    const int E = in_sizes[2];       // 1600000

    // workspace layout
    char* w = (char*)d_ws;
    size_t o = 0;
    int* counts   = (int*)(w + o); o += (size_t)N * 4;
    int* offsets  = (int*)(w + o); o += (size_t)(N + 1) * 4;
    int* cursor   = (int*)(w + o); o += (size_t)N * 4;
    int* partials = (int*)(w + o); o += 4096 * 4;
    o = (o + 15) & ~(size_t)15;
    float4* ginp  = (float4*)(w + o); o += (size_t)E * 16;
    float* agg    = (float*)(w + o);  o += (size_t)N * HID * 4;

    const int nb1 = (N + 1023) / 1024;

    hipMemsetAsync(counts, 0, (size_t)N * 4, stream);
    hipMemsetAsync(agg, 0, (size_t)N * HID * 4, stream);
    count_kernel<<<(E + 255) / 256, 256, 0, stream>>>(ei, counts, E);
    scan1_kernel<<<nb1, 256, 0, stream>>>(counts, partials, N);
    scan2_kernel<<<1, 256, 0, stream>>>(partials, nb1, offsets, N);
    scan3_kernel<<<nb1, 256, 0, stream>>>(counts, partials, offsets, cursor, N);
    fill_kernel<<<(E + 255) / 256, 256, 0, stream>>>(x, ei, ea, cursor, ginp, E);
    edge_mlp_kernel<<<(E + 127) / 128, 128, 0, stream>>>(ginp, W1, b1, W2, b2, agg, E);
    node_kernel<<<(N + 255) / 256, 256, 0, stream>>>(x, u, batch, W3, b3, W4, b4, W5, b5,
                                                     agg, counts, (float*)d_out, N);
}

// Round 4
// 395.097 us; speedup vs baseline: 13.8018x; 1.1201x over previous
//
#include <hip/hip_runtime.h>

// Node model GNN, CSR-pull + MFMA edge MLP + wave segmented-reduce:
//   edge MLP: h = relu(relu([x[src],ea]@W1+b1)@W2+b2)   (W3 commuted past the mean)
//   agg[n][j] = sum_{e: dst(e)=n} h[e][j]
//   node: a3 = (agg/cnt)@W3+b3; out = relu([x,a3,u[batch]]@W4+b4)@W5+b5
constexpr int HID = 64;

typedef __attribute__((ext_vector_type(8))) short s8v;    // 8 bf16 (4 VGPR) MFMA A/B frag
typedef __attribute__((ext_vector_type(4))) float f32x4;  // MFMA C/D frag
typedef unsigned long long ull;

__device__ __forceinline__ void atomF(float* p, float v) {
    __hip_atomic_fetch_add(p, v, __ATOMIC_RELAXED, __HIP_MEMORY_SCOPE_AGENT);
}

// ---------- pass 0: split W2 into transposed bf16 hi/lo tables ----------
// Bhi/Blo[f][k] = bf16 split of W2[k][f]; B-fragment reads become contiguous 16B.
__global__ __launch_bounds__(64) void pack_w2_kernel(
    const float* __restrict__ W2, unsigned short* __restrict__ Bhi,
    unsigned short* __restrict__ Blo)
{
    const int f = threadIdx.x;
    for (int k = 0; k < 64; ++k) {
        const float w = W2[k * 64 + f];
        const unsigned int u = __float_as_uint(w);
        const float hf = __uint_as_float(u & 0xffff0000u);   // truncated hi
        const float r = w - hf;                              // exact residual
        Bhi[f * 64 + k] = (unsigned short)(u >> 16);
        Blo[f * 64 + k] = (unsigned short)(__float_as_uint(r) >> 16);
    }
}

// ---------- pass 1: in-degree histogram ----------
__global__ __launch_bounds__(256) void count_kernel(
    const int* __restrict__ ei, int* __restrict__ counts, int E)
{
    int e = blockIdx.x * 256 + threadIdx.x;
    if (e < E) atomicAdd(&counts[ei[E + e]], 1);
}

// ---------- pass 2a ----------
__global__ __launch_bounds__(256) void scan1_kernel(
    const int* __restrict__ counts, int* __restrict__ partials, int N)
{
    __shared__ int red[256];
    const int base = blockIdx.x * 1024;
    int s = 0;
    #pragma unroll
    for (int r = 0; r < 4; ++r) {
        int i = base + r * 256 + threadIdx.x;
        s += (i < N) ? counts[i] : 0;
    }
    red[threadIdx.x] = s;
    __syncthreads();
    for (int off = 128; off > 0; off >>= 1) {
        if (threadIdx.x < off) red[threadIdx.x] += red[threadIdx.x + off];
        __syncthreads();
    }
    if (threadIdx.x == 0) partials[blockIdx.x] = red[0];
}

// ---------- pass 2b ----------
__global__ __launch_bounds__(256) void scan2_kernel(
    int* __restrict__ partials, int nb, int* __restrict__ offsets, int N)
{
    __shared__ int sm[256];
    __shared__ int carry_s;
    if (threadIdx.x == 0) carry_s = 0;
    __syncthreads();
    for (int base = 0; base < nb; base += 256) {
        int i = base + threadIdx.x;
        int v = (i < nb) ? partials[i] : 0;
        sm[threadIdx.x] = v;
        __syncthreads();
        for (int off = 1; off < 256; off <<= 1) {
            int t = (threadIdx.x >= off) ? sm[threadIdx.x - off] : 0;
            __syncthreads();
            sm[threadIdx.x] += t;
            __syncthreads();
        }
        int incl = sm[threadIdx.x];
        int carry = carry_s;
        __syncthreads();
        if (i < nb) partials[i] = incl - v + carry;
        if (threadIdx.x == 255) carry_s = carry + incl;
        __syncthreads();
    }
    if (threadIdx.x == 0) offsets[N] = carry_s;
}

// ---------- pass 2c ----------
__global__ __launch_bounds__(256) void scan3_kernel(
    const int* __restrict__ counts, const int* __restrict__ partials,
    int* __restrict__ offsets, int* __restrict__ cursor, int N)
{
    __shared__ int sm[256];
    const int tid = threadIdx.x;
    const int i0 = blockIdx.x * 1024 + tid * 4;
    int v[4];
    #pragma unroll
    for (int r = 0; r < 4; ++r) v[r] = (i0 + r < N) ? counts[i0 + r] : 0;
    const int tsum = v[0] + v[1] + v[2] + v[3];
    sm[tid] = tsum;
    __syncthreads();
    for (int off = 1; off < 256; off <<= 1) {
        int t = (tid >= off) ? sm[tid - off] : 0;
        __syncthreads();
        sm[tid] += t;
        __syncthreads();
    }
    int excl = sm[tid] - tsum + partials[blockIdx.x];
    #pragma unroll
    for (int r = 0; r < 4; ++r) {
        if (i0 + r < N) { offsets[i0 + r] = excl; cursor[i0 + r] = excl; }
        excl += v[r];
    }
}

// ---------- pass 3: gather edge inputs into dest-sorted float4 (dest in .w) ----------
__global__ __launch_bounds__(256) void fill_kernel(
    const float* __restrict__ x, const int* __restrict__ ei,
    const float* __restrict__ ea, int* __restrict__ cursor,
    float4* __restrict__ ginp, int E)
{
    int e = blockIdx.x * 256 + threadIdx.x;
    if (e >= E) return;
    const int src = ei[e];
    const int dst = ei[E + e];
    const float w = ea[e];
    const float2 xv = ((const float2*)x)[src];
    const int pos = atomicAdd(&cursor[dst], 1);
    ginp[pos] = make_float4(xv.x, xv.y, w, __int_as_float(dst));
}

// ---------- pass 4: MFMA edge MLP + wave segmented reduce ----------
// Per wave (64 sorted edges, wave-autonomous, no barriers):
//  1. h1 = relu(L1) in fp32, hi/lo bf16 split, staged to LDS [edge][feat] XOR-swizzled
//  2. H2 = H1@W2 via 96x mfma_16x16x32_bf16 (hi*Whi + hi*Wlo + lo*Whi)
//  3. bias+relu -> hT[feat][edge] (XOR-swizzled, reuses frag LDS)
//  4. lane=feature serial walk, flush runs as coalesced 256B atomic bursts
__global__ __launch_bounds__(128) void edge_mlp_kernel(
    const float4* __restrict__ ginp,
    const float* __restrict__ W1, const float* __restrict__ b1,
    const unsigned short* __restrict__ Bhi, const unsigned short* __restrict__ Blo,
    const float* __restrict__ b2,
    float* __restrict__ agg, int E)
{
    __shared__ __align__(16) unsigned int smem[2 * 4096];   // 16KB/wave union region
    const int tid  = threadIdx.x;
    const int wv   = tid >> 6;
    const int lane = tid & 63;
    unsigned int* ws = smem + wv * 4096;
    char* wsb = (char*)ws;

    const int e = blockIdx.x * 128 + wv * 64 + lane;
    float4 g = make_float4(0.f, 0.f, 0.f, __int_as_float(-1));
    if (e < E) g = ginp[e];
    const int dst = __float_as_int(g.w);

    const int dprev = __shfl_up(dst, 1);
    const bool start = (lane == 0) || (dprev != dst);
    const ull bmask = __ballot(start);
    const ull fmask = (bmask >> 1) | (1ull << 63);

    // ---- phase 1: h1 + split, LDS hi at [0,8KB), lo at [8KB,16KB) ----
    const int rsw = (lane & 7) << 4;
    #pragma unroll
    for (int jc = 0; jc < 8; ++jc) {
        unsigned int hp[4], lp[4];
        #pragma unroll
        for (int jp = 0; jp < 4; ++jp) {
            const int j0 = jc * 8 + jp * 2;
            float v0 = fmaf(g.x, W1[j0],     fmaf(g.y, W1[64 + j0],     fmaf(g.z, W1[128 + j0],     b1[j0])));
            float v1 = fmaf(g.x, W1[j0 + 1], fmaf(g.y, W1[64 + j0 + 1], fmaf(g.z, W1[128 + j0 + 1], b1[j0 + 1])));
            v0 = fmaxf(v0, 0.f); v1 = fmaxf(v1, 0.f);
            const unsigned int u0 = __float_as_uint(v0), u1 = __float_as_uint(v1);
            hp[jp] = (u0 >> 16) | (u1 & 0xffff0000u);
            const float r0 = v0 - __uint_as_float(u0 & 0xffff0000u);
            const float r1 = v1 - __uint_as_float(u1 & 0xffff0000u);
            lp[jp] = (__float_as_uint(r0) >> 16) | (__float_as_uint(r1) & 0xffff0000u);
        }
        const int boff = (lane * 128 + jc * 16) ^ rsw;
        *(uint4*)(wsb + boff)        = make_uint4(hp[0], hp[1], hp[2], hp[3]);
        *(uint4*)(wsb + 8192 + boff) = make_uint4(lp[0], lp[1], lp[2], lp[3]);
    }

    // ---- phase 2: MFMA ----
    f32x4 acc[4][4];
    #pragma unroll
    for (int a = 0; a < 4; ++a)
        #pragma unroll
        for (int b = 0; b < 4; ++b) acc[a][b] = (f32x4){0.f, 0.f, 0.f, 0.f};

    const int am = lane & 15, aq = lane >> 4;
    #pragma unroll
    for (int kb = 0; kb < 2; ++kb) {
        s8v ah[4], al[4], bh[4], bl[4];
        #pragma unroll
        for (int eb = 0; eb < 4; ++eb) {
            const int ar = eb * 16 + am;                       // A row (edge)
            const int ao = (ar * 128 + (kb * 32 + aq * 8) * 2) ^ ((ar & 7) << 4);
            ah[eb] = *(const s8v*)(wsb + ao);
            al[eb] = *(const s8v*)(wsb + 8192 + ao);
        }
        #pragma unroll
        for (int fb = 0; fb < 4; ++fb) {
            const int bo = (fb * 16 + am) * 64 + kb * 32 + aq * 8;  // B col (feat), k-run
            bh[fb] = *(const s8v*)(Bhi + bo);
            bl[fb] = *(const s8v*)(Blo + bo);
        }
        #pragma unroll
        for (int eb = 0; eb < 4; ++eb)
            #pragma unroll
            for (int fb = 0; fb < 4; ++fb) {
                acc[eb][fb] = __builtin_amdgcn_mfma_f32_16x16x32_bf16(ah[eb], bh[fb], acc[eb][fb], 0, 0, 0);
                acc[eb][fb] = __builtin_amdgcn_mfma_f32_16x16x32_bf16(ah[eb], bl[fb], acc[eb][fb], 0, 0, 0);
                acc[eb][fb] = __builtin_amdgcn_mfma_f32_16x16x32_bf16(al[eb], bh[fb], acc[eb][fb], 0, 0, 0);
            }
    }

    // ---- phase 3: bias+relu -> hT[feat][edge^] (reuses frag LDS; in-order DS per wave) ----
    float bias[4];
    #pragma unroll
    for (int fb = 0; fb < 4; ++fb) bias[fb] = b2[fb * 16 + am];
    #pragma unroll
    for (int eb = 0; eb < 4; ++eb)
        #pragma unroll
        for (int fb = 0; fb < 4; ++fb) {
            const int feat = fb * 16 + am;
            #pragma unroll
            for (int r = 0; r < 4; ++r) {
                const int edge = eb * 16 + aq * 4 + r;         // D row mapping
                const float v = fmaxf(acc[eb][fb][r] + bias[fb], 0.f);
                ws[feat * 64 + (edge ^ (feat & 31))] = __float_as_uint(v);
            }
        }

    // ---- phase 4: segmented reduce, lane = feature ----
    const int fx = lane & 31;
    float a2 = 0.f;
    #pragma unroll
    for (int e2 = 0; e2 < 64; ++e2) {
        a2 += __uint_as_float(ws[lane * 64 + (e2 ^ fx)]);
        if ((fmask >> e2) & 1ull) {
            const int d = __shfl(dst, e2);
            if (d >= 0) atomF(&agg[(size_t)d * HID + lane], a2);
            a2 = 0.f;
        }
    }
}

// ---------- pass 5: node MLP ----------
__global__ __launch_bounds__(256) void node_kernel(
    const float* __restrict__ x, const float* __restrict__ u,
    const int* __restrict__ batch,
    const float* __restrict__ W3, const float* __restrict__ b3,
    const float* __restrict__ W4, const float* __restrict__ b4,
    const float* __restrict__ W5, const float* __restrict__ b5,
    const float* __restrict__ agg, const int* __restrict__ counts,
    float* __restrict__ out, int N)
{
    const int n = blockIdx.x * 256 + threadIdx.x;
    if (n >= N) return;

    const float inv = 1.f / fmaxf((float)counts[n], 1.f);
    const float4* ar = (const float4*)(agg + (size_t)n * HID);

    float a3[HID];
    #pragma unroll
    for (int j = 0; j < HID; ++j) a3[j] = b3[j];
    #pragma unroll 4
    for (int q = 0; q < HID / 4; ++q) {
        const float4 m4 = ar[q];
        const float mk[4] = {m4.x * inv, m4.y * inv, m4.z * inv, m4.w * inv};
        #pragma unroll
        for (int r = 0; r < 4; ++r) {
            const float* wr = W3 + (q * 4 + r) * HID;
            #pragma unroll
            for (int j = 0; j < HID; ++j) a3[j] = fmaf(mk[r], wr[j], a3[j]);
        }
    }

    const float2 xv = ((const float2*)x)[n];
    const float ub = u[batch[n]];
    float acc[67];
    #pragma unroll
    for (int j = 0; j < 67; ++j) acc[j] = b4[j];
    #pragma unroll
    for (int j = 0; j < 67; ++j) acc[j] = fmaf(xv.x, W4[j], acc[j]);
    #pragma unroll
    for (int j = 0; j < 67; ++j) acc[j] = fmaf(xv.y, W4[67 + j], acc[j]);
    #pragma unroll 4
    for (int k = 0; k < HID; ++k) {
        const float* wr = W4 + (2 + k) * 67;
        #pragma unroll
        for (int j = 0; j < 67; ++j) acc[j] = fmaf(a3[k], wr[j], acc[j]);
    }
    #pragma unroll
    for (int j = 0; j < 67; ++j) acc[j] = fmaf(ub, W4[66 * 67 + j], acc[j]);

    float o0 = b5[0], o1 = b5[1];
    #pragma unroll
    for (int j = 0; j < 67; ++j) {
        const float z = fmaxf(acc[j], 0.f);
        o0 = fmaf(z, W5[2 * j], o0);
        o1 = fmaf(z, W5[2 * j + 1], o1);
    }
    out[2 * n] = o0;
    out[2 * n + 1] = o1;
}

extern "C" void kernel_launch(void* const* d_in, const int* in_sizes, int n_in,
                              void* d_out, int out_size, void* d_ws, size_t ws_size,
                              hipStream_t stream) {
    const float* x     = (const float*)d_in[0];
    const int*   ei    = (const int*)  d_in[1];
    const float* ea    = (const float*)d_in[2];
    const float* u     = (const float*)d_in[3];
    const int*   batch = (const int*)  d_in[4];
    const float* W1 = (const float*)d_in[5];  const float* b1 = (const float*)d_in[6];
    const float* W2 = (const float*)d_in[7];  const float* b2 = (const float*)d_in[8];
    const float* W3 = (const float*)d_in[9];  const float* b3 = (const float*)d_in[10];
    const float* W4 = (const float*)d_in[11]; const float* b4 = (const float*)d_in[12];
    const float* W5 = (const float*)d_in[13]; const float* b5 = (const float*)d_in[14];

    const int N = in_sizes[0] / 2;   // 100000
    const int E = in_sizes[2];       // 1600000

    // workspace layout
    char* w = (char*)d_ws;
    size_t o = 0;
    int* counts   = (int*)(w + o); o += (size_t)N * 4;
    int* offsets  = (int*)(w + o); o += (size_t)(N + 1) * 4;
    int* cursor   = (int*)(w + o); o += (size_t)N * 4;
    int* partials = (int*)(w + o); o += 4096 * 4;
    o = (o + 15) & ~(size_t)15;
    unsigned short* Bhi = (unsigned short*)(w + o); o += 64 * 64 * 2;
    unsigned short* Blo = (unsigned short*)(w + o); o += 64 * 64 * 2;
    o = (o + 15) & ~(size_t)15;
    float4* ginp  = (float4*)(w + o); o += (size_t)E * 16;
    float* agg    = (float*)(w + o);  o += (size_t)N * HID * 4;

    const int nb1 = (N + 1023) / 1024;

    hipMemsetAsync(counts, 0, (size_t)N * 4, stream);
    hipMemsetAsync(agg, 0, (size_t)N * HID * 4, stream);
    pack_w2_kernel<<<1, 64, 0, stream>>>(W2, Bhi, Blo);
    count_kernel<<<(E + 255) / 256, 256, 0, stream>>>(ei, counts, E);
    scan1_kernel<<<nb1, 256, 0, stream>>>(counts, partials, N);
    scan2_kernel<<<1, 256, 0, stream>>>(partials, nb1, offsets, N);
    scan3_kernel<<<nb1, 256, 0, stream>>>(counts, partials, offsets, cursor, N);
    fill_kernel<<<(E + 255) / 256, 256, 0, stream>>>(x, ei, ea, cursor, ginp, E);
    edge_mlp_kernel<<<(E + 127) / 128, 128, 0, stream>>>(ginp, W1, b1, Bhi, Blo, b2, agg, E);
    node_kernel<<<(N + 255) / 256, 256, 0, stream>>>(x, u, batch, W3, b3, W4, b4, W5, b5,
                                                     agg, counts, (float*)d_out, N);
}

// Round 5
// 317.059 us; speedup vs baseline: 17.1989x; 1.2461x over previous
//
#include <hip/hip_runtime.h>

// Node model GNN, CSR-pull + MFMA edge MLP + wave segmented-reduce:
//   edge MLP: h = relu(relu([x[src],ea]@W1+b1)@W2+b2)   (W3 commuted past the mean)
//   agg[n][j] = sum_{e: dst(e)=n} h[e][j]
//   node: out = relu([x, mean@W3+b3, u]@W4+b4)@W5+b5
//         = relu(mean@(W3@W4mid) + x-terms + (b4+b3@W4mid))@W5+b5   (W3 folded into W4)
constexpr int HID = 64;

typedef __attribute__((ext_vector_type(8))) short s8v;    // 8 bf16 (4 VGPR) MFMA A/B frag
typedef __attribute__((ext_vector_type(4))) float f32x4;  // MFMA C/D frag
typedef unsigned long long ull;

__device__ __forceinline__ void atomF(float* p, float v) {
    __hip_atomic_fetch_add(p, v, __ATOMIC_RELAXED, __HIP_MEMORY_SCOPE_AGENT);
}

// ---------- pass 0a: split W2 into transposed bf16 hi/lo tables (parallel) ----------
__global__ __launch_bounds__(64) void pack_w2_kernel(
    const float* __restrict__ W2, unsigned short* __restrict__ Bhi,
    unsigned short* __restrict__ Blo)
{
    const int f = blockIdx.x;    // 64 blocks
    const int k = threadIdx.x;   // 64 threads
    const float w = W2[k * 64 + f];
    const unsigned int u = __float_as_uint(w);
    const float hf = __uint_as_float(u & 0xffff0000u);
    const float r = w - hf;
    Bhi[f * 64 + k] = (unsigned short)(u >> 16);
    Blo[f * 64 + k] = (unsigned short)(__float_as_uint(r) >> 16);
}

// ---------- pass 0b: fold W3 into W4's middle rows: C = W3@W4[2:66,:], b4' = b4 + b3@W4[2:66,:] ----------
__global__ __launch_bounds__(128) void pack_w34_kernel(
    const float* __restrict__ W3, const float* __restrict__ b3,
    const float* __restrict__ W4, const float* __restrict__ b4,
    float* __restrict__ C, float* __restrict__ b4p)
{
    const int t = blockIdx.x;    // 0..64; t==64 computes the folded bias
    const int j = threadIdx.x;
    if (j >= 67) return;
    if (t < 64) {
        float s = 0.f;
        for (int k = 0; k < 64; ++k) s = fmaf(W3[t * 64 + k], W4[(2 + k) * 67 + j], s);
        C[t * 67 + j] = s;
    } else {
        float s = b4[j];
        for (int k = 0; k < 64; ++k) s = fmaf(b3[k], W4[(2 + k) * 67 + j], s);
        b4p[j] = s;
    }
}

// ---------- pass 1: in-degree histogram ----------
__global__ __launch_bounds__(256) void count_kernel(
    const int* __restrict__ ei, int* __restrict__ counts, int E)
{
    int e = blockIdx.x * 256 + threadIdx.x;
    if (e < E) atomicAdd(&counts[ei[E + e]], 1);
}

// ---------- pass 2a ----------
__global__ __launch_bounds__(256) void scan1_kernel(
    const int* __restrict__ counts, int* __restrict__ partials, int N)
{
    __shared__ int red[256];
    const int base = blockIdx.x * 1024;
    int s = 0;
    #pragma unroll
    for (int r = 0; r < 4; ++r) {
        int i = base + r * 256 + threadIdx.x;
        s += (i < N) ? counts[i] : 0;
    }
    red[threadIdx.x] = s;
    __syncthreads();
    for (int off = 128; off > 0; off >>= 1) {
        if (threadIdx.x < off) red[threadIdx.x] += red[threadIdx.x + off];
        __syncthreads();
    }
    if (threadIdx.x == 0) partials[blockIdx.x] = red[0];
}

// ---------- pass 2b ----------
__global__ __launch_bounds__(256) void scan2_kernel(
    int* __restrict__ partials, int nb, int* __restrict__ offsets, int N)
{
    __shared__ int sm[256];
    __shared__ int carry_s;
    if (threadIdx.x == 0) carry_s = 0;
    __syncthreads();
    for (int base = 0; base < nb; base += 256) {
        int i = base + threadIdx.x;
        int v = (i < nb) ? partials[i] : 0;
        sm[threadIdx.x] = v;
        __syncthreads();
        for (int off = 1; off < 256; off <<= 1) {
            int t = (threadIdx.x >= off) ? sm[threadIdx.x - off] : 0;
            __syncthreads();
            sm[threadIdx.x] += t;
            __syncthreads();
        }
        int incl = sm[threadIdx.x];
        int carry = carry_s;
        __syncthreads();
        if (i < nb) partials[i] = incl - v + carry;
        if (threadIdx.x == 255) carry_s = carry + incl;
        __syncthreads();
    }
    if (threadIdx.x == 0) offsets[N] = carry_s;
}

// ---------- pass 2c ----------
__global__ __launch_bounds__(256) void scan3_kernel(
    const int* __restrict__ counts, const int* __restrict__ partials,
    int* __restrict__ offsets, int* __restrict__ cursor, int N)
{
    __shared__ int sm[256];
    const int tid = threadIdx.x;
    const int i0 = blockIdx.x * 1024 + tid * 4;
    int v[4];
    #pragma unroll
    for (int r = 0; r < 4; ++r) v[r] = (i0 + r < N) ? counts[i0 + r] : 0;
    const int tsum = v[0] + v[1] + v[2] + v[3];
    sm[tid] = tsum;
    __syncthreads();
    for (int off = 1; off < 256; off <<= 1) {
        int t = (tid >= off) ? sm[tid - off] : 0;
        __syncthreads();
        sm[tid] += t;
        __syncthreads();
    }
    int excl = sm[tid] - tsum + partials[blockIdx.x];
    #pragma unroll
    for (int r = 0; r < 4; ++r) {
        if (i0 + r < N) { offsets[i0 + r] = excl; cursor[i0 + r] = excl; }
        excl += v[r];
    }
}

// ---------- pass 3: gather edge inputs into dest-sorted float4 (dest in .w) ----------
__global__ __launch_bounds__(256) void fill_kernel(
    const float* __restrict__ x, const int* __restrict__ ei,
    const float* __restrict__ ea, int* __restrict__ cursor,
    float4* __restrict__ ginp, int E)
{
    int e = blockIdx.x * 256 + threadIdx.x;
    if (e >= E) return;
    const int src = ei[e];
    const int dst = ei[E + e];
    const float w = ea[e];
    const float2 xv = ((const float2*)x)[src];
    const int pos = atomicAdd(&cursor[dst], 1);
    ginp[pos] = make_float4(xv.x, xv.y, w, __int_as_float(dst));
}

// ---------- pass 4: MFMA edge MLP + wave segmented reduce (8KB LDS per wave) ----------
// k-split staging: stage feats [kb*32, kb*32+32) hi|lo interleaved per-edge in ONE 8KB
// buffer, read kb frags, MFMA, overwrite for next kb. Walk runs in two 32-edge halves
// in the same 8KB. Wave-autonomous (per-wave LDS ops are in-order); compiler fences
// keep the reuse ordering.
__global__ __launch_bounds__(128, 3) void edge_mlp_kernel(
    const float4* __restrict__ ginp,
    const float* __restrict__ W1, const float* __restrict__ b1,
    const unsigned short* __restrict__ Bhi, const unsigned short* __restrict__ Blo,
    const float* __restrict__ b2,
    float* __restrict__ agg, int E)
{
    __shared__ __align__(16) unsigned int smem[2 * 2048];   // 8KB per wave
    const int tid  = threadIdx.x;
    const int wv   = tid >> 6;
    const int lane = tid & 63;
    unsigned int* ws = smem + wv * 2048;
    char* wsb = (char*)ws;

    const int e = blockIdx.x * 128 + wv * 64 + lane;
    float4 g = make_float4(0.f, 0.f, 0.f, __int_as_float(-1));
    if (e < E) g = ginp[e];
    const int dst = __float_as_int(g.w);

    const int dprev = __shfl_up(dst, 1);
    const bool startb = (lane == 0) || (dprev != dst);
    const ull bmask = __ballot(startb);
    const ull fmask = (bmask >> 1) | (1ull << 63);

    const int am = lane & 15, aq = lane >> 4;
    const int rsw = (lane & 7) << 4;

    f32x4 acc[4][4];
    #pragma unroll
    for (int a = 0; a < 4; ++a)
        #pragma unroll
        for (int b = 0; b < 4; ++b) acc[a][b] = (f32x4){0.f, 0.f, 0.f, 0.f};

    #pragma unroll
    for (int kb = 0; kb < 2; ++kb) {
        // phase 1: feats kb*32..kb*32+31; per-edge 128B row = [hi 64B | lo 64B], XOR-swizzled
        #pragma unroll
        for (int jc = 0; jc < 4; ++jc) {
            unsigned int hp[4], lp[4];
            #pragma unroll
            for (int jp = 0; jp < 4; ++jp) {
                const int j0 = kb * 32 + jc * 8 + jp * 2;
                float v0 = fmaf(g.x, W1[j0],     fmaf(g.y, W1[64 + j0],     fmaf(g.z, W1[128 + j0],     b1[j0])));
                float v1 = fmaf(g.x, W1[j0 + 1], fmaf(g.y, W1[64 + j0 + 1], fmaf(g.z, W1[128 + j0 + 1], b1[j0 + 1])));
                v0 = fmaxf(v0, 0.f); v1 = fmaxf(v1, 0.f);
                const unsigned int u0 = __float_as_uint(v0), u1 = __float_as_uint(v1);
                hp[jp] = (u0 >> 16) | (u1 & 0xffff0000u);
                const float r0 = v0 - __uint_as_float(u0 & 0xffff0000u);
                const float r1 = v1 - __uint_as_float(u1 & 0xffff0000u);
                lp[jp] = (__float_as_uint(r0) >> 16) | (__float_as_uint(r1) & 0xffff0000u);
            }
            const int boff = (lane * 128 + jc * 16) ^ rsw;
            *(uint4*)(wsb + boff)        = make_uint4(hp[0], hp[1], hp[2], hp[3]);
            *(uint4*)(wsb + (boff ^ 64)) = make_uint4(lp[0], lp[1], lp[2], lp[3]);
        }

        // frag reads for this kb
        s8v ah[4], al[4], bh[4], bl[4];
        #pragma unroll
        for (int eb = 0; eb < 4; ++eb) {
            const int ar = eb * 16 + am;
            const int ao = (ar * 128 + aq * 16) ^ ((ar & 7) << 4);
            ah[eb] = *(const s8v*)(wsb + ao);
            al[eb] = *(const s8v*)(wsb + (ao ^ 64));
        }
        #pragma unroll
        for (int fb = 0; fb < 4; ++fb) {
            const int bo = (fb * 16 + am) * 64 + kb * 32 + aq * 8;
            bh[fb] = *(const s8v*)(Bhi + bo);
            bl[fb] = *(const s8v*)(Blo + bo);
        }
        asm volatile("" ::: "memory");   // keep next-kb stores after this kb's LDS reads

        #pragma unroll
        for (int eb = 0; eb < 4; ++eb)
            #pragma unroll
            for (int fb = 0; fb < 4; ++fb) {
                acc[eb][fb] = __builtin_amdgcn_mfma_f32_16x16x32_bf16(ah[eb], bh[fb], acc[eb][fb], 0, 0, 0);
                acc[eb][fb] = __builtin_amdgcn_mfma_f32_16x16x32_bf16(ah[eb], bl[fb], acc[eb][fb], 0, 0, 0);
                acc[eb][fb] = __builtin_amdgcn_mfma_f32_16x16x32_bf16(al[eb], bh[fb], acc[eb][fb], 0, 0, 0);
            }
    }

    // phase 3+4 in two 32-edge halves, reusing the same 8KB
    float bias[4];
    #pragma unroll
    for (int fb = 0; fb < 4; ++fb) bias[fb] = b2[fb * 16 + am];

    const int fx = lane & 31;
    float a2 = 0.f;
    #pragma unroll
    for (int h = 0; h < 2; ++h) {
        asm volatile("" ::: "memory");   // prior reads (frags / walk h-1) before overwrite
        #pragma unroll
        for (int ebh = 0; ebh < 2; ++ebh) {
            const int eb = h * 2 + ebh;
            #pragma unroll
            for (int fb = 0; fb < 4; ++fb) {
                const int feat = fb * 16 + am;
                #pragma unroll
                for (int r = 0; r < 4; ++r) {
                    const int eh = ebh * 16 + aq * 4 + r;
                    const float v = fmaxf(acc[eb][fb][r] + bias[fb], 0.f);
                    ws[feat * 32 + (eh ^ (feat & 31))] = __float_as_uint(v);
                }
            }
        }
        asm volatile("" ::: "memory");   // writes before walk reads
        #pragma unroll
        for (int eh = 0; eh < 32; ++eh) {
            const int e2 = h * 32 + eh;
            a2 += __uint_as_float(ws[lane * 32 + (eh ^ fx)]);
            if ((fmask >> e2) & 1ull) {                     // wave-uniform
                const int d = __shfl(dst, e2);
                if (d >= 0) atomF(&agg[(size_t)d * HID + lane], a2);
                a2 = 0.f;
            }
        }
    }
}

// ---------- pass 5: node MLP (W3 pre-folded into C) ----------
__global__ __launch_bounds__(256) void node_kernel(
    const float* __restrict__ x, const float* __restrict__ u,
    const int* __restrict__ batch,
    const float* __restrict__ W4, const float* __restrict__ W5,
    const float* __restrict__ b5,
    const float* __restrict__ C, const float* __restrict__ b4p,
    const float* __restrict__ agg, const int* __restrict__ counts,
    float* __restrict__ out, int N)
{
    const int n = blockIdx.x * 256 + threadIdx.x;
    if (n >= N) return;

    const float inv = 1.f / fmaxf((float)counts[n], 1.f);
    const float4* ar = (const float4*)(agg + (size_t)n * HID);

    float acc[67];
    #pragma unroll
    for (int j = 0; j < 67; ++j) acc[j] = b4p[j];

    #pragma unroll 4
    for (int q = 0; q < 16; ++q) {
        const float4 m4 = ar[q];
        const float mk[4] = {m4.x * inv, m4.y * inv, m4.z * inv, m4.w * inv};
        #pragma unroll
        for (int r = 0; r < 4; ++r) {
            const float* cr = C + (q * 4 + r) * 67;
            #pragma unroll
            for (int j = 0; j < 67; ++j) acc[j] = fmaf(mk[r], cr[j], acc[j]);
        }
    }

    const float2 xv = ((const float2*)x)[n];
    const float ub = u[batch[n]];
    #pragma unroll
    for (int j = 0; j < 67; ++j) acc[j] = fmaf(xv.x, W4[j], acc[j]);
    #pragma unroll
    for (int j = 0; j < 67; ++j) acc[j] = fmaf(xv.y, W4[67 + j], acc[j]);
    #pragma unroll
    for (int j = 0; j < 67; ++j) acc[j] = fmaf(ub, W4[66 * 67 + j], acc[j]);

    float o0 = b5[0], o1 = b5[1];
    #pragma unroll
    for (int j = 0; j < 67; ++j) {
        const float z = fmaxf(acc[j], 0.f);
        o0 = fmaf(z, W5[2 * j], o0);
        o1 = fmaf(z, W5[2 * j + 1], o1);
    }
    out[2 * n] = o0;
    out[2 * n + 1] = o1;
}

extern "C" void kernel_launch(void* const* d_in, const int* in_sizes, int n_in,
                              void* d_out, int out_size, void* d_ws, size_t ws_size,
                              hipStream_t stream) {
    const float* x     = (const float*)d_in[0];
    const int*   ei    = (const int*)  d_in[1];
    const float* ea    = (const float*)d_in[2];
    const float* u     = (const float*)d_in[3];
    const int*   batch = (const int*)  d_in[4];
    const float* W1 = (const float*)d_in[5];  const float* b1 = (const float*)d_in[6];
    const float* W2 = (const float*)d_in[7];  const float* b2 = (const float*)d_in[8];
    const float* W3 = (const float*)d_in[9];  const float* b3 = (const float*)d_in[10];
    const float* W4 = (const float*)d_in[11]; const float* b4 = (const float*)d_in[12];
    const float* W5 = (const float*)d_in[13]; const float* b5 = (const float*)d_in[14];

    const int N = in_sizes[0] / 2;   // 100000
    const int E = in_sizes[2];       // 1600000

    // workspace layout
    char* w = (char*)d_ws;
    size_t o = 0;
    int* counts   = (int*)(w + o); o += (size_t)N * 4;
    int* offsets  = (int*)(w + o); o += (size_t)(N + 1) * 4;
    int* cursor   = (int*)(w + o); o += (size_t)N * 4;
    int* partials = (int*)(w + o); o += 4096 * 4;
    o = (o + 15) & ~(size_t)15;
    unsigned short* Bhi = (unsigned short*)(w + o); o += 64 * 64 * 2;
    unsigned short* Blo = (unsigned short*)(w + o); o += 64 * 64 * 2;
    float* Cmat = (float*)(w + o); o += 64 * 67 * 4;
    float* b4p  = (float*)(w + o); o += 68 * 4;
    o = (o + 15) & ~(size_t)15;
    float4* ginp  = (float4*)(w + o); o += (size_t)E * 16;
    float* agg    = (float*)(w + o);  o += (size_t)N * HID * 4;

    const int nb1 = (N + 1023) / 1024;

    hipMemsetAsync(counts, 0, (size_t)N * 4, stream);
    hipMemsetAsync(agg, 0, (size_t)N * HID * 4, stream);
    pack_w2_kernel<<<64, 64, 0, stream>>>(W2, Bhi, Blo);
    pack_w34_kernel<<<65, 128, 0, stream>>>(W3, b3, W4, b4, Cmat, b4p);
    count_kernel<<<(E + 255) / 256, 256, 0, stream>>>(ei, counts, E);
    scan1_kernel<<<nb1, 256, 0, stream>>>(counts, partials, N);
    scan2_kernel<<<1, 256, 0, stream>>>(partials, nb1, offsets, N);
    scan3_kernel<<<nb1, 256, 0, stream>>>(counts, partials, offsets, cursor, N);
    fill_kernel<<<(E + 255) / 256, 256, 0, stream>>>(x, ei, ea, cursor, ginp, E);
    edge_mlp_kernel<<<(E + 127) / 128, 128, 0, stream>>>(ginp, W1, b1, Bhi, Blo, b2, agg, E);
    node_kernel<<<(N + 255) / 256, 256, 0, stream>>>(x, u, batch, W4, W5, b5, Cmat, b4p,
                                                     agg, counts, (float*)d_out, N);
}